// Round 1
// baseline (856.084 us; speedup 1.0000x reference)
//
#include <hip/hip_runtime.h>
#include <hip/hip_bf16.h>
#include <math.h>

#define NODES 50000
#define FEAT 128

__global__ void k_zero(int* __restrict__ p, int n) {
  int i = blockIdx.x * blockDim.x + threadIdx.x;
  if (i < n) p[i] = 0;
}

__global__ void k_hist(const int* __restrict__ src, const int* __restrict__ dst,
                       int* __restrict__ deg, int E) {
  int e = blockIdx.x * blockDim.x + threadIdx.x;
  if (e < E) {
    atomicAdd(&deg[src[e]], 1);
    atomicAdd(&deg[dst[e]], 1);
  }
}

__global__ void k_scan_block(const int* __restrict__ deg, int* __restrict__ offs,
                             int* __restrict__ bsum, int n) {
  __shared__ int s[256];
  int t = threadIdx.x;
  int i = blockIdx.x * 256 + t;
  int v = (i < n) ? deg[i] : 0;
  s[t] = v;
  __syncthreads();
  for (int off = 1; off < 256; off <<= 1) {
    int u = (t >= off) ? s[t - off] : 0;
    __syncthreads();
    s[t] += u;
    __syncthreads();
  }
  if (i < n) offs[i] = s[t] - v;      // exclusive within block
  if (t == 255) bsum[blockIdx.x] = s[255];
}

__global__ void k_scan_top(int* __restrict__ bsum, int nb) {
  __shared__ int s[256];
  int t = threadIdx.x;
  int v = (t < nb) ? bsum[t] : 0;
  s[t] = v;
  __syncthreads();
  for (int off = 1; off < 256; off <<= 1) {
    int u = (t >= off) ? s[t - off] : 0;
    __syncthreads();
    s[t] += u;
    __syncthreads();
  }
  if (t < nb) bsum[t] = s[t] - v;     // exclusive
}

__global__ void k_scan_add(int* __restrict__ offs, const int* __restrict__ bsum,
                           int* __restrict__ cursor, int n, int total) {
  int i = blockIdx.x * blockDim.x + threadIdx.x;
  if (i < n) {
    int o = offs[i] + bsum[i >> 8];
    offs[i] = o;
    cursor[i] = o;
  }
  if (i == 0) offs[n] = total;
}

__global__ void k_scatter(const int* __restrict__ src, const int* __restrict__ dst,
                          int* __restrict__ cursor, int* __restrict__ adj, int E) {
  int e = blockIdx.x * blockDim.x + threadIdx.x;
  if (e < E) {
    int s = src[e], d = dst[e];
    adj[atomicAdd(&cursor[d], 1)] = s;
    adj[atomicAdd(&cursor[s], 1)] = d;
  }
}

// aggr[i][f] = (deg>0) ? max_{j in N(i)} h[j][f] - h[i][f] : 0
__global__ __launch_bounds__(256) void k_nmax(
    const float* __restrict__ h, const int* __restrict__ offs,
    const int* __restrict__ adj, float* __restrict__ aggr) {
  int i = blockIdx.x * 2 + (threadIdx.x >> 7);
  int f = threadIdx.x & 127;
  int o0 = offs[i], o1 = offs[i + 1];
  float m = -INFINITY;
  int e = o0;
  for (; e + 2 <= o1; e += 2) {
    int j0 = adj[e], j1 = adj[e + 1];
    float v0 = h[j0 * FEAT + f];
    float v1 = h[j1 * FEAT + f];
    m = fmaxf(m, fmaxf(v0, v1));
  }
  if (e < o1) {
    int j0 = adj[e];
    m = fmaxf(m, h[j0 * FEAT + f]);
  }
  aggr[i * FEAT + f] = (o1 > o0) ? (m - h[i * FEAT + f]) : 0.0f;
}

// out = relu([A1 | A2] @ W + bias), W is [256][128] row-major
__global__ __launch_bounds__(256) void k_gemm(
    const float* __restrict__ A1, const float* __restrict__ A2,
    const float* __restrict__ W, const float* __restrict__ bias,
    float* __restrict__ out, int N) {
  __shared__ float As[64][20];
  __shared__ float Bs[16][128];
  int t = threadIdx.x;
  int m0 = blockIdx.x * 64;
  int tr = t >> 4, tc = t & 15;
  float acc[4][8];
#pragma unroll
  for (int i = 0; i < 4; ++i)
#pragma unroll
    for (int j = 0; j < 8; ++j) acc[i][j] = 0.f;

  int arow = t >> 2;
  int ac4 = (t & 3) << 2;
  int brow = t >> 5;
  int bc4 = (t & 31) << 2;
  int gr = m0 + arow;

  for (int kstep = 0; kstep < 16; ++kstep) {
    int ks = kstep << 4;
    const float* __restrict__ Asrc = (kstep < 8) ? A1 : A2;
    int kcol = ks & 127;
    float4 av = make_float4(0.f, 0.f, 0.f, 0.f);
    if (gr < N) av = *(const float4*)&Asrc[gr * FEAT + kcol + ac4];
    float4 bv0 = *(const float4*)&W[(ks + brow) * FEAT + bc4];
    float4 bv1 = *(const float4*)&W[(ks + brow + 8) * FEAT + bc4];
    __syncthreads();
    *(float4*)&As[arow][ac4] = av;
    *(float4*)&Bs[brow][bc4] = bv0;
    *(float4*)&Bs[brow + 8][bc4] = bv1;
    __syncthreads();
#pragma unroll
    for (int kk = 0; kk < 16; ++kk) {
      float a[4];
      a[0] = As[tr * 4 + 0][kk];
      a[1] = As[tr * 4 + 1][kk];
      a[2] = As[tr * 4 + 2][kk];
      a[3] = As[tr * 4 + 3][kk];
      float4 b0 = *(float4*)&Bs[kk][tc * 4];
      float4 b1 = *(float4*)&Bs[kk][tc * 4 + 64];
      float b[8] = {b0.x, b0.y, b0.z, b0.w, b1.x, b1.y, b1.z, b1.w};
#pragma unroll
      for (int i = 0; i < 4; ++i)
#pragma unroll
        for (int j = 0; j < 8; ++j) acc[i][j] += a[i] * b[j];
    }
  }

  float4 bias0 = *(const float4*)&bias[tc * 4];
  float4 bias1 = *(const float4*)&bias[tc * 4 + 64];
#pragma unroll
  for (int i = 0; i < 4; ++i) {
    int r = m0 + tr * 4 + i;
    if (r < N) {
      float4 o0, o1;
      o0.x = fmaxf(acc[i][0] + bias0.x, 0.f);
      o0.y = fmaxf(acc[i][1] + bias0.y, 0.f);
      o0.z = fmaxf(acc[i][2] + bias0.z, 0.f);
      o0.w = fmaxf(acc[i][3] + bias0.w, 0.f);
      o1.x = fmaxf(acc[i][4] + bias1.x, 0.f);
      o1.y = fmaxf(acc[i][5] + bias1.y, 0.f);
      o1.z = fmaxf(acc[i][6] + bias1.z, 0.f);
      o1.w = fmaxf(acc[i][7] + bias1.w, 0.f);
      *(float4*)&out[r * FEAT + tc * 4] = o0;
      *(float4*)&out[r * FEAT + tc * 4 + 64] = o1;
    }
  }
}

// block-local running max over 64 sorted nodes, flush with int-atomicMax (vals >= 0)
__global__ __launch_bounds__(128) void k_pool(
    const float* __restrict__ h, const int* __restrict__ batch,
    float* __restrict__ g, int N) {
  int f = threadIdx.x;
  int base = blockIdx.x * 64;
  int end = min(base + 64, N);
  int cur = -1;
  float m = 0.f;
  for (int n = base; n < end; ++n) {
    int b = batch[n];
    if (b != cur) {
      if (cur >= 0) atomicMax((int*)&g[cur * FEAT + f], __float_as_int(m));
      cur = b;
      m = 0.f;
    }
    m = fmaxf(m, h[n * FEAT + f]);
  }
  if (cur >= 0) atomicMax((int*)&g[cur * FEAT + f], __float_as_int(m));
}

__global__ __launch_bounds__(64) void k_mlp(
    const float* __restrict__ g, const float* __restrict__ Wf1,
    const float* __restrict__ bf1, const float* __restrict__ Wf2,
    const float* __restrict__ bf2, float* __restrict__ out) {
  __shared__ float gr[128];
  __shared__ float h1[64];
  int gi = blockIdx.x, t = threadIdx.x;
  gr[t] = g[gi * FEAT + t];
  gr[t + 64] = g[gi * FEAT + 64 + t];
  __syncthreads();
  float acc = bf1[t];
#pragma unroll 4
  for (int k = 0; k < 128; ++k) acc += gr[k] * Wf1[k * 64 + t];
  h1[t] = fmaxf(acc, 0.f);
  __syncthreads();
  float logit = -INFINITY;
  if (t < 40) {
    float a = bf2[t];
#pragma unroll 4
    for (int k = 0; k < 64; ++k) a += h1[k] * Wf2[k * 40 + t];
    logit = a;
  }
  float m = logit;
#pragma unroll
  for (int off = 32; off; off >>= 1) m = fmaxf(m, __shfl_xor(m, off));
  float e = (t < 40) ? expf(logit - m) : 0.f;
  float s = e;
#pragma unroll
  for (int off = 32; off; off >>= 1) s += __shfl_xor(s, off);
  if (t < 40) out[gi * 40 + t] = logit - m - logf(s);
}

extern "C" void kernel_launch(void* const* d_in, const int* in_sizes, int n_in,
                              void* d_out, int out_size, void* d_ws, size_t ws_size,
                              hipStream_t stream) {
  const float* x = (const float*)d_in[0];
  const int* ei = (const int*)d_in[1];
  const int* batch = (const int*)d_in[2];
  const float* W1 = (const float*)d_in[3];
  const float* b1 = (const float*)d_in[4];
  const float* W2 = (const float*)d_in[5];
  const float* b2 = (const float*)d_in[6];
  const float* W3 = (const float*)d_in[7];
  const float* b3 = (const float*)d_in[8];
  const float* Wf1 = (const float*)d_in[9];
  const float* bf1 = (const float*)d_in[10];
  const float* Wf2 = (const float*)d_in[11];
  const float* bf2 = (const float*)d_in[12];
  float* out = (float*)d_out;

  const int N = NODES;
  const int E = in_sizes[1] / 2;  // 800000 original edges
  const int* src = ei;
  const int* dst = ei + E;

  char* ws = (char*)d_ws;
  size_t off = 0;
  auto carve = [&](size_t bytes) {
    void* p = ws + off;
    off += (bytes + 255) & ~(size_t)255;
    return p;
  };
  float* hA = (float*)carve((size_t)N * FEAT * 4);
  float* hB = (float*)carve((size_t)N * FEAT * 4);
  float* aggr = (float*)carve((size_t)N * FEAT * 4);
  float* g = (float*)carve((size_t)64 * FEAT * 4);
  int* deg = (int*)carve((size_t)N * 4);
  int* offs = (int*)carve((size_t)(N + 1) * 4);
  int* cursor = (int*)carve((size_t)N * 4);
  int* bsum = (int*)carve(256 * 4);
  int* adj = (int*)carve((size_t)2 * E * 4);

  // ---- build undirected CSR (counting sort by node) ----
  k_zero<<<(N + 255) / 256, 256, 0, stream>>>(deg, N);
  k_zero<<<(64 * FEAT + 255) / 256, 256, 0, stream>>>((int*)g, 64 * FEAT);
  k_hist<<<(E + 255) / 256, 256, 0, stream>>>(src, dst, deg, E);
  int nb = (N + 255) / 256;  // 196
  k_scan_block<<<nb, 256, 0, stream>>>(deg, offs, bsum, N);
  k_scan_top<<<1, 256, 0, stream>>>(bsum, nb);
  k_scan_add<<<nb, 256, 0, stream>>>(offs, bsum, cursor, N, 2 * E);
  k_scatter<<<(E + 255) / 256, 256, 0, stream>>>(src, dst, cursor, adj, E);

  // ---- 3x MRConv (neighbor-max, concat-GEMM, ReLU) ----
  k_nmax<<<N / 2, 256, 0, stream>>>(x, offs, adj, aggr);
  k_gemm<<<(N + 63) / 64, 256, 0, stream>>>(x, aggr, W1, b1, hA, N);
  k_nmax<<<N / 2, 256, 0, stream>>>(hA, offs, adj, aggr);
  k_gemm<<<(N + 63) / 64, 256, 0, stream>>>(hA, aggr, W2, b2, hB, N);
  k_nmax<<<N / 2, 256, 0, stream>>>(hB, offs, adj, aggr);
  k_gemm<<<(N + 63) / 64, 256, 0, stream>>>(hB, aggr, W3, b3, hA, N);

  // ---- global max pool + MLP head + log_softmax ----
  k_pool<<<(N + 63) / 64, 128, 0, stream>>>(hA, batch, g, N);
  k_mlp<<<64, 64, 0, stream>>>(g, Wf1, bf1, Wf2, bf2, out);
}

// Round 2
// 688.621 us; speedup vs baseline: 1.2432x; 1.2432x over previous
//
#include <hip/hip_runtime.h>
#include <hip/hip_bf16.h>
#include <math.h>

#define NODES 50000
#define FEAT 128
#define NB 196          // ceil(50000/256) buckets of 256 nodes
#define BCAP 12288      // per-bucket adj capacity (mean 8192, sd ~90)

__global__ void k_zero(int* __restrict__ p, int n) {
  int i = blockIdx.x * blockDim.x + threadIdx.x;
  if (i < n) p[i] = 0;
}

// Pass A: coarse bucket histogram (bucket = node >> 8), LDS-aggregated
__global__ __launch_bounds__(256) void k_bcount(const int* __restrict__ src,
                                                const int* __restrict__ dst,
                                                int E, int* __restrict__ bcount) {
  __shared__ int cnt[NB];
  int t = threadIdx.x;
  for (int i = t; i < NB; i += 256) cnt[i] = 0;
  __syncthreads();
  int base = blockIdx.x * 4096;
  int nE = min(4096, E - base);
  for (int k = t; k < nE; k += 256) {
    int s = src[base + k], d = dst[base + k];
    atomicAdd(&cnt[d >> 8], 1);
    atomicAdd(&cnt[s >> 8], 1);
  }
  __syncthreads();
  for (int i = t; i < NB; i += 256)
    if (cnt[i]) atomicAdd(&bcount[i], cnt[i]);
}

// exclusive scan of NB bucket counts -> bbase[NB+1]
__global__ __launch_bounds__(256) void k_bscan(const int* __restrict__ bcount,
                                               int* __restrict__ bbase, int twoE) {
  __shared__ int sc[256];
  int t = threadIdx.x;
  int v = (t < NB) ? bcount[t] : 0;
  sc[t] = v;
  __syncthreads();
  for (int off = 1; off < 256; off <<= 1) {
    int u = (t >= off) ? sc[t - off] : 0;
    __syncthreads();
    sc[t] += u;
    __syncthreads();
  }
  if (t < NB) bbase[t] = sc[t] - v;
  if (t == 0) bbase[NB] = twoE;
}

// Pass B: bucket-sort (d,s) pairs via LDS staging, flush in contiguous runs
__global__ __launch_bounds__(256) void k_bin(const int* __restrict__ src,
                                             const int* __restrict__ dst, int E,
                                             const int* __restrict__ bbase,
                                             int* __restrict__ bcur,
                                             uint2* __restrict__ binned) {
  __shared__ uint2 stage[8192];
  __shared__ int cnt[NB];
  __shared__ int lbase[NB];
  __shared__ int gbase[NB];
  __shared__ int lcur[NB];
  __shared__ int sc[256];
  int t = threadIdx.x;
  for (int i = t; i < NB; i += 256) cnt[i] = 0;
  __syncthreads();
  int base = blockIdx.x * 4096;
  int nE = min(4096, E - base);
  for (int k = t; k < nE; k += 256) {
    int s = src[base + k], d = dst[base + k];
    atomicAdd(&cnt[d >> 8], 1);
    atomicAdd(&cnt[s >> 8], 1);
  }
  __syncthreads();
  int v = (t < NB) ? cnt[t] : 0;
  sc[t] = v;
  __syncthreads();
  for (int off = 1; off < 256; off <<= 1) {
    int u = (t >= off) ? sc[t - off] : 0;
    __syncthreads();
    sc[t] += u;
    __syncthreads();
  }
  if (t < NB) {
    lbase[t] = sc[t] - v;
    lcur[t] = sc[t] - v;
  }
  __syncthreads();
  int total = sc[255];
  for (int k = t; k < nE; k += 256) {
    int s = src[base + k], d = dst[base + k];
    int p1 = atomicAdd(&lcur[d >> 8], 1);
    stage[p1] = make_uint2((unsigned)d, (unsigned)s);
    int p2 = atomicAdd(&lcur[s >> 8], 1);
    stage[p2] = make_uint2((unsigned)s, (unsigned)d);
  }
  __syncthreads();
  if (t < NB && cnt[t] > 0) gbase[t] = bbase[t] + atomicAdd(&bcur[t], cnt[t]);
  __syncthreads();
  for (int k = t; k < total; k += 256) {
    uint2 p = stage[k];
    int b = p.x >> 8;
    binned[gbase[b] + (k - lbase[b])] = p;
  }
}

// Pass C: per-bucket local CSR build entirely in LDS, coalesced writeout
__global__ __launch_bounds__(256) void k_build(const int* __restrict__ bbase,
                                               const uint2* __restrict__ binned,
                                               int* __restrict__ offs,
                                               int* __restrict__ adj,
                                               int N, int twoE) {
  __shared__ int hist[256];
  __shared__ int sc[256];
  __shared__ int lcur[256];
  __shared__ int adjS[BCAP];
  int b = blockIdx.x, t = threadIdx.x;
  int lo = bbase[b], hi = bbase[b + 1];
  int cntb = hi - lo;
  hist[t] = 0;
  __syncthreads();
  for (int k = t; k < cntb; k += 256) {
    uint2 p = binned[lo + k];
    atomicAdd(&hist[p.x & 255], 1);
  }
  __syncthreads();
  int v = hist[t];
  sc[t] = v;
  __syncthreads();
  for (int off = 1; off < 256; off <<= 1) {
    int u = (t >= off) ? sc[t - off] : 0;
    __syncthreads();
    sc[t] += u;
    __syncthreads();
  }
  int excl = sc[t] - v;
  lcur[t] = excl;
  int node = (b << 8) + t;
  if (node < N) offs[node] = lo + excl;
  if (b == NB - 1 && t == 0) offs[N] = twoE;
  __syncthreads();
  for (int k = t; k < cntb; k += 256) {
    uint2 p = binned[lo + k];
    int pos = atomicAdd(&lcur[p.x & 255], 1);
    adjS[pos] = (int)p.y;
  }
  __syncthreads();
  for (int k = t; k < cntb; k += 256) adj[lo + k] = adjS[k];
}

// aggr[i][f] = (deg>0) ? max_{j in N(i)} h[j][f] - h[i][f] : 0
__global__ __launch_bounds__(256) void k_nmax(
    const float* __restrict__ h, const int* __restrict__ offs,
    const int* __restrict__ adj, float* __restrict__ aggr) {
  int i = blockIdx.x * 2 + (threadIdx.x >> 7);
  int f = threadIdx.x & 127;
  int o0 = offs[i], o1 = offs[i + 1];
  float m = -INFINITY;
  int e = o0;
  for (; e + 2 <= o1; e += 2) {
    int j0 = adj[e], j1 = adj[e + 1];
    float v0 = h[j0 * FEAT + f];
    float v1 = h[j1 * FEAT + f];
    m = fmaxf(m, fmaxf(v0, v1));
  }
  if (e < o1) {
    int j0 = adj[e];
    m = fmaxf(m, h[j0 * FEAT + f]);
  }
  aggr[i * FEAT + f] = (o1 > o0) ? (m - h[i * FEAT + f]) : 0.0f;
}

// out = relu([A1 | A2] @ W + bias), W is [256][128] row-major
__global__ __launch_bounds__(256) void k_gemm(
    const float* __restrict__ A1, const float* __restrict__ A2,
    const float* __restrict__ W, const float* __restrict__ bias,
    float* __restrict__ out, int N) {
  __shared__ float As[64][20];
  __shared__ float Bs[16][128];
  int t = threadIdx.x;
  int m0 = blockIdx.x * 64;
  int tr = t >> 4, tc = t & 15;
  float acc[4][8];
#pragma unroll
  for (int i = 0; i < 4; ++i)
#pragma unroll
    for (int j = 0; j < 8; ++j) acc[i][j] = 0.f;

  int arow = t >> 2;
  int ac4 = (t & 3) << 2;
  int brow = t >> 5;
  int bc4 = (t & 31) << 2;
  int gr = m0 + arow;

  for (int kstep = 0; kstep < 16; ++kstep) {
    int ks = kstep << 4;
    const float* __restrict__ Asrc = (kstep < 8) ? A1 : A2;
    int kcol = ks & 127;
    float4 av = make_float4(0.f, 0.f, 0.f, 0.f);
    if (gr < N) av = *(const float4*)&Asrc[gr * FEAT + kcol + ac4];
    float4 bv0 = *(const float4*)&W[(ks + brow) * FEAT + bc4];
    float4 bv1 = *(const float4*)&W[(ks + brow + 8) * FEAT + bc4];
    __syncthreads();
    *(float4*)&As[arow][ac4] = av;
    *(float4*)&Bs[brow][bc4] = bv0;
    *(float4*)&Bs[brow + 8][bc4] = bv1;
    __syncthreads();
#pragma unroll
    for (int kk = 0; kk < 16; ++kk) {
      float a[4];
      a[0] = As[tr * 4 + 0][kk];
      a[1] = As[tr * 4 + 1][kk];
      a[2] = As[tr * 4 + 2][kk];
      a[3] = As[tr * 4 + 3][kk];
      float4 b0 = *(float4*)&Bs[kk][tc * 4];
      float4 b1 = *(float4*)&Bs[kk][tc * 4 + 64];
      float b[8] = {b0.x, b0.y, b0.z, b0.w, b1.x, b1.y, b1.z, b1.w};
#pragma unroll
      for (int i = 0; i < 4; ++i)
#pragma unroll
        for (int j = 0; j < 8; ++j) acc[i][j] += a[i] * b[j];
    }
  }

  float4 bias0 = *(const float4*)&bias[tc * 4];
  float4 bias1 = *(const float4*)&bias[tc * 4 + 64];
#pragma unroll
  for (int i = 0; i < 4; ++i) {
    int r = m0 + tr * 4 + i;
    if (r < N) {
      float4 o0, o1;
      o0.x = fmaxf(acc[i][0] + bias0.x, 0.f);
      o0.y = fmaxf(acc[i][1] + bias0.y, 0.f);
      o0.z = fmaxf(acc[i][2] + bias0.z, 0.f);
      o0.w = fmaxf(acc[i][3] + bias0.w, 0.f);
      o1.x = fmaxf(acc[i][4] + bias1.x, 0.f);
      o1.y = fmaxf(acc[i][5] + bias1.y, 0.f);
      o1.z = fmaxf(acc[i][6] + bias1.z, 0.f);
      o1.w = fmaxf(acc[i][7] + bias1.w, 0.f);
      *(float4*)&out[r * FEAT + tc * 4] = o0;
      *(float4*)&out[r * FEAT + tc * 4 + 64] = o1;
    }
  }
}

// block-local running max over 64 sorted nodes, flush with int-atomicMax (vals >= 0)
__global__ __launch_bounds__(128) void k_pool(
    const float* __restrict__ h, const int* __restrict__ batch,
    float* __restrict__ g, int N) {
  int f = threadIdx.x;
  int base = blockIdx.x * 64;
  int end = min(base + 64, N);
  int cur = -1;
  float m = 0.f;
  for (int n = base; n < end; ++n) {
    int b = batch[n];
    if (b != cur) {
      if (cur >= 0) atomicMax((int*)&g[cur * FEAT + f], __float_as_int(m));
      cur = b;
      m = 0.f;
    }
    m = fmaxf(m, h[n * FEAT + f]);
  }
  if (cur >= 0) atomicMax((int*)&g[cur * FEAT + f], __float_as_int(m));
}

__global__ __launch_bounds__(64) void k_mlp(
    const float* __restrict__ g, const float* __restrict__ Wf1,
    const float* __restrict__ bf1, const float* __restrict__ Wf2,
    const float* __restrict__ bf2, float* __restrict__ out) {
  __shared__ float gr[128];
  __shared__ float h1[64];
  int gi = blockIdx.x, t = threadIdx.x;
  gr[t] = g[gi * FEAT + t];
  gr[t + 64] = g[gi * FEAT + 64 + t];
  __syncthreads();
  float acc = bf1[t];
#pragma unroll 4
  for (int k = 0; k < 128; ++k) acc += gr[k] * Wf1[k * 64 + t];
  h1[t] = fmaxf(acc, 0.f);
  __syncthreads();
  float logit = -INFINITY;
  if (t < 40) {
    float a = bf2[t];
#pragma unroll 4
    for (int k = 0; k < 64; ++k) a += h1[k] * Wf2[k * 40 + t];
    logit = a;
  }
  float m = logit;
#pragma unroll
  for (int off = 32; off; off >>= 1) m = fmaxf(m, __shfl_xor(m, off));
  float e = (t < 40) ? expf(logit - m) : 0.f;
  float s = e;
#pragma unroll
  for (int off = 32; off; off >>= 1) s += __shfl_xor(s, off);
  if (t < 40) out[gi * 40 + t] = logit - m - logf(s);
}

extern "C" void kernel_launch(void* const* d_in, const int* in_sizes, int n_in,
                              void* d_out, int out_size, void* d_ws, size_t ws_size,
                              hipStream_t stream) {
  const float* x = (const float*)d_in[0];
  const int* ei = (const int*)d_in[1];
  const int* batch = (const int*)d_in[2];
  const float* W1 = (const float*)d_in[3];
  const float* b1 = (const float*)d_in[4];
  const float* W2 = (const float*)d_in[5];
  const float* b2 = (const float*)d_in[6];
  const float* W3 = (const float*)d_in[7];
  const float* b3 = (const float*)d_in[8];
  const float* Wf1 = (const float*)d_in[9];
  const float* bf1 = (const float*)d_in[10];
  const float* Wf2 = (const float*)d_in[11];
  const float* bf2 = (const float*)d_in[12];
  float* out = (float*)d_out;

  const int N = NODES;
  const int E = in_sizes[1] / 2;  // 800000 original edges
  const int* src = ei;
  const int* dst = ei + E;

  char* ws = (char*)d_ws;
  size_t off = 0;
  auto carve = [&](size_t bytes) {
    void* p = ws + off;
    off += (bytes + 255) & ~(size_t)255;
    return p;
  };
  float* hA = (float*)carve((size_t)N * FEAT * 4);
  float* hB = (float*)carve((size_t)N * FEAT * 4);
  float* aggr = (float*)carve((size_t)N * FEAT * 4);  // aliased: binned lives here during build
  int* zreg = (int*)carve((size_t)(256 + 256 + 64 * FEAT) * 4);  // bcount | bcur | g (contig)
  int* bcount = zreg;
  int* bcur = zreg + 256;
  float* g = (float*)(zreg + 512);
  int* bbase = (int*)carve((size_t)(NB + 1) * 4);
  int* offs = (int*)carve((size_t)(N + 1) * 4);
  int* adj = (int*)carve((size_t)2 * E * 4);
  uint2* binned = (uint2*)aggr;  // 12.8 MB <= 25.6 MB, dead until first k_nmax

  const int nzero = 256 + 256 + 64 * FEAT;
  const int nEB = (E + 4095) / 4096;  // 196 edge-chunk blocks

  // ---- build undirected CSR (two-level binned counting sort, coalesced writes) ----
  k_zero<<<(nzero + 255) / 256, 256, 0, stream>>>(zreg, nzero);
  k_bcount<<<nEB, 256, 0, stream>>>(src, dst, E, bcount);
  k_bscan<<<1, 256, 0, stream>>>(bcount, bbase, 2 * E);
  k_bin<<<nEB, 256, 0, stream>>>(src, dst, E, bbase, bcur, binned);
  k_build<<<NB, 256, 0, stream>>>(bbase, binned, offs, adj, N, 2 * E);

  // ---- 3x MRConv (neighbor-max, concat-GEMM, ReLU) ----
  k_nmax<<<N / 2, 256, 0, stream>>>(x, offs, adj, aggr);
  k_gemm<<<(N + 63) / 64, 256, 0, stream>>>(x, aggr, W1, b1, hA, N);
  k_nmax<<<N / 2, 256, 0, stream>>>(hA, offs, adj, aggr);
  k_gemm<<<(N + 63) / 64, 256, 0, stream>>>(hA, aggr, W2, b2, hB, N);
  k_nmax<<<N / 2, 256, 0, stream>>>(hB, offs, adj, aggr);
  k_gemm<<<(N + 63) / 64, 256, 0, stream>>>(hB, aggr, W3, b3, hA, N);

  // ---- global max pool + MLP head + log_softmax ----
  k_pool<<<(N + 63) / 64, 128, 0, stream>>>(hA, batch, g, N);
  k_mlp<<<64, 64, 0, stream>>>(g, Wf1, bf1, Wf2, bf2, out);
}

// Round 3
// 528.400 us; speedup vs baseline: 1.6201x; 1.3032x over previous
//
#include <hip/hip_runtime.h>
#include <hip/hip_bf16.h>
#include <math.h>

#define NODES 50000
#define FEAT 128
#define NB 196          // ceil(50000/256) buckets of 256 nodes
#define BCAP 12288      // per-bucket adj capacity (mean 8192, sd ~90)

__device__ __forceinline__ unsigned bf16rne(float x) {
  unsigned u = __float_as_uint(x);
  return (u + 0x7FFFu + ((u >> 16) & 1u)) >> 16;  // round-to-nearest-even, result in low 16
}

__global__ void k_zero(int* __restrict__ p, int n) {
  int i = blockIdx.x * blockDim.x + threadIdx.x;
  if (i < n) p[i] = 0;
}

// fp32 [N][128] -> packed bf16 pairs [N][64] u32
__global__ __launch_bounds__(256) void k_cast(const float* __restrict__ in,
                                              unsigned* __restrict__ out, int n2) {
  int i = blockIdx.x * 256 + threadIdx.x;
  if (i < n2) {
    float2 v = ((const float2*)in)[i];
    out[i] = bf16rne(v.x) | (bf16rne(v.y) << 16);
  }
}

// Pass A: coarse bucket histogram (bucket = node >> 8), LDS-aggregated
__global__ __launch_bounds__(256) void k_bcount(const int* __restrict__ src,
                                                const int* __restrict__ dst,
                                                int E, int* __restrict__ bcount) {
  __shared__ int cnt[NB];
  int t = threadIdx.x;
  for (int i = t; i < NB; i += 256) cnt[i] = 0;
  __syncthreads();
  int base = blockIdx.x * 4096;
  int nE = min(4096, E - base);
  for (int k = t; k < nE; k += 256) {
    int s = src[base + k], d = dst[base + k];
    atomicAdd(&cnt[d >> 8], 1);
    atomicAdd(&cnt[s >> 8], 1);
  }
  __syncthreads();
  for (int i = t; i < NB; i += 256)
    if (cnt[i]) atomicAdd(&bcount[i], cnt[i]);
}

// exclusive scan of NB bucket counts -> bbase[NB+1]
__global__ __launch_bounds__(256) void k_bscan(const int* __restrict__ bcount,
                                               int* __restrict__ bbase, int twoE) {
  __shared__ int sc[256];
  int t = threadIdx.x;
  int v = (t < NB) ? bcount[t] : 0;
  sc[t] = v;
  __syncthreads();
  for (int off = 1; off < 256; off <<= 1) {
    int u = (t >= off) ? sc[t - off] : 0;
    __syncthreads();
    sc[t] += u;
    __syncthreads();
  }
  if (t < NB) bbase[t] = sc[t] - v;
  if (t == 0) bbase[NB] = twoE;
}

// Pass B: bucket-sort (d,s) pairs via LDS staging, flush in contiguous runs
__global__ __launch_bounds__(256) void k_bin(const int* __restrict__ src,
                                             const int* __restrict__ dst, int E,
                                             const int* __restrict__ bbase,
                                             int* __restrict__ bcur,
                                             uint2* __restrict__ binned) {
  __shared__ uint2 stage[8192];
  __shared__ int cnt[NB];
  __shared__ int lbase[NB];
  __shared__ int gbase[NB];
  __shared__ int lcur[NB];
  __shared__ int sc[256];
  int t = threadIdx.x;
  for (int i = t; i < NB; i += 256) cnt[i] = 0;
  __syncthreads();
  int base = blockIdx.x * 4096;
  int nE = min(4096, E - base);
  for (int k = t; k < nE; k += 256) {
    int s = src[base + k], d = dst[base + k];
    atomicAdd(&cnt[d >> 8], 1);
    atomicAdd(&cnt[s >> 8], 1);
  }
  __syncthreads();
  int v = (t < NB) ? cnt[t] : 0;
  sc[t] = v;
  __syncthreads();
  for (int off = 1; off < 256; off <<= 1) {
    int u = (t >= off) ? sc[t - off] : 0;
    __syncthreads();
    sc[t] += u;
    __syncthreads();
  }
  if (t < NB) {
    lbase[t] = sc[t] - v;
    lcur[t] = sc[t] - v;
  }
  __syncthreads();
  int total = sc[255];
  for (int k = t; k < nE; k += 256) {
    int s = src[base + k], d = dst[base + k];
    int p1 = atomicAdd(&lcur[d >> 8], 1);
    stage[p1] = make_uint2((unsigned)d, (unsigned)s);
    int p2 = atomicAdd(&lcur[s >> 8], 1);
    stage[p2] = make_uint2((unsigned)s, (unsigned)d);
  }
  __syncthreads();
  if (t < NB && cnt[t] > 0) gbase[t] = bbase[t] + atomicAdd(&bcur[t], cnt[t]);
  __syncthreads();
  for (int k = t; k < total; k += 256) {
    uint2 p = stage[k];
    int b = p.x >> 8;
    binned[gbase[b] + (k - lbase[b])] = p;
  }
}

// Pass C: per-bucket local CSR build entirely in LDS, coalesced writeout
__global__ __launch_bounds__(256) void k_build(const int* __restrict__ bbase,
                                               const uint2* __restrict__ binned,
                                               int* __restrict__ offs,
                                               int* __restrict__ adj,
                                               int N, int twoE) {
  __shared__ int hist[256];
  __shared__ int sc[256];
  __shared__ int lcur[256];
  __shared__ int adjS[BCAP];
  int b = blockIdx.x, t = threadIdx.x;
  int lo = bbase[b], hi = bbase[b + 1];
  int cntb = hi - lo;
  hist[t] = 0;
  __syncthreads();
  for (int k = t; k < cntb; k += 256) {
    uint2 p = binned[lo + k];
    atomicAdd(&hist[p.x & 255], 1);
  }
  __syncthreads();
  int v = hist[t];
  sc[t] = v;
  __syncthreads();
  for (int off = 1; off < 256; off <<= 1) {
    int u = (t >= off) ? sc[t - off] : 0;
    __syncthreads();
    sc[t] += u;
    __syncthreads();
  }
  int excl = sc[t] - v;
  lcur[t] = excl;
  int node = (b << 8) + t;
  if (node < N) offs[node] = lo + excl;
  if (b == NB - 1 && t == 0) offs[N] = twoE;
  __syncthreads();
  for (int k = t; k < cntb; k += 256) {
    uint2 p = binned[lo + k];
    int pos = atomicAdd(&lcur[p.x & 255], 1);
    adjS[pos] = (int)p.y;
  }
  __syncthreads();
  for (int k = t; k < cntb; k += 256) adj[lo + k] = adjS[k];
}

// aggr[i][f] = (deg>0) ? max_{j in N(i)} bf16(h[j][f]) - h[i][f] : 0
// one wave per node; lane handles features {2l, 2l+1} via packed-bf16 u32 gather
__global__ __launch_bounds__(256) void k_nmax(
    const unsigned* __restrict__ h16, const float* __restrict__ h,
    const int* __restrict__ offs, const int* __restrict__ adj,
    float* __restrict__ aggr) {
  int i = blockIdx.x * 4 + (threadIdx.x >> 6);
  int lane = threadIdx.x & 63;
  int o0 = offs[i], o1 = offs[i + 1];
  float mlo0 = -INFINITY, mhi0 = -INFINITY;
  float mlo1 = -INFINITY, mhi1 = -INFINITY;
  int e = o0;
  for (; e + 4 <= o1; e += 4) {
    int j0 = adj[e], j1 = adj[e + 1], j2 = adj[e + 2], j3 = adj[e + 3];
    unsigned u0 = h16[j0 * 64 + lane];
    unsigned u1 = h16[j1 * 64 + lane];
    unsigned u2 = h16[j2 * 64 + lane];
    unsigned u3 = h16[j3 * 64 + lane];
    mlo0 = fmaxf(mlo0, __uint_as_float(u0 << 16));
    mhi0 = fmaxf(mhi0, __uint_as_float(u0 & 0xFFFF0000u));
    mlo1 = fmaxf(mlo1, __uint_as_float(u1 << 16));
    mhi1 = fmaxf(mhi1, __uint_as_float(u1 & 0xFFFF0000u));
    mlo0 = fmaxf(mlo0, __uint_as_float(u2 << 16));
    mhi0 = fmaxf(mhi0, __uint_as_float(u2 & 0xFFFF0000u));
    mlo1 = fmaxf(mlo1, __uint_as_float(u3 << 16));
    mhi1 = fmaxf(mhi1, __uint_as_float(u3 & 0xFFFF0000u));
  }
  for (; e < o1; ++e) {
    unsigned u0 = h16[adj[e] * 64 + lane];
    mlo0 = fmaxf(mlo0, __uint_as_float(u0 << 16));
    mhi0 = fmaxf(mhi0, __uint_as_float(u0 & 0xFFFF0000u));
  }
  float mlo = fmaxf(mlo0, mlo1), mhi = fmaxf(mhi0, mhi1);
  float2 hv = ((const float2*)h)[i * 64 + lane];
  float2 r;
  r.x = (o1 > o0) ? (mlo - hv.x) : 0.f;
  r.y = (o1 > o0) ? (mhi - hv.y) : 0.f;
  ((float2*)aggr)[i * 64 + lane] = r;
}

// out = relu([A1 | A2] @ W + bias); also (optionally) writes packed-bf16 copy
__global__ __launch_bounds__(256) void k_gemm(
    const float* __restrict__ A1, const float* __restrict__ A2,
    const float* __restrict__ W, const float* __restrict__ bias,
    float* __restrict__ out, unsigned* __restrict__ out16, int N) {
  __shared__ float As[64][20];
  __shared__ float Bs[16][128];
  int t = threadIdx.x;
  int m0 = blockIdx.x * 64;
  int tr = t >> 4, tc = t & 15;
  float acc[4][8];
#pragma unroll
  for (int i = 0; i < 4; ++i)
#pragma unroll
    for (int j = 0; j < 8; ++j) acc[i][j] = 0.f;

  int arow = t >> 2;
  int ac4 = (t & 3) << 2;
  int brow = t >> 5;
  int bc4 = (t & 31) << 2;
  int gr = m0 + arow;

  for (int kstep = 0; kstep < 16; ++kstep) {
    int ks = kstep << 4;
    const float* __restrict__ Asrc = (kstep < 8) ? A1 : A2;
    int kcol = ks & 127;
    float4 av = make_float4(0.f, 0.f, 0.f, 0.f);
    if (gr < N) av = *(const float4*)&Asrc[gr * FEAT + kcol + ac4];
    float4 bv0 = *(const float4*)&W[(ks + brow) * FEAT + bc4];
    float4 bv1 = *(const float4*)&W[(ks + brow + 8) * FEAT + bc4];
    __syncthreads();
    *(float4*)&As[arow][ac4] = av;
    *(float4*)&Bs[brow][bc4] = bv0;
    *(float4*)&Bs[brow + 8][bc4] = bv1;
    __syncthreads();
#pragma unroll
    for (int kk = 0; kk < 16; ++kk) {
      float a[4];
      a[0] = As[tr * 4 + 0][kk];
      a[1] = As[tr * 4 + 1][kk];
      a[2] = As[tr * 4 + 2][kk];
      a[3] = As[tr * 4 + 3][kk];
      float4 b0 = *(float4*)&Bs[kk][tc * 4];
      float4 b1 = *(float4*)&Bs[kk][tc * 4 + 64];
      float b[8] = {b0.x, b0.y, b0.z, b0.w, b1.x, b1.y, b1.z, b1.w};
#pragma unroll
      for (int i = 0; i < 4; ++i)
#pragma unroll
        for (int j = 0; j < 8; ++j) acc[i][j] += a[i] * b[j];
    }
  }

  float4 bias0 = *(const float4*)&bias[tc * 4];
  float4 bias1 = *(const float4*)&bias[tc * 4 + 64];
#pragma unroll
  for (int i = 0; i < 4; ++i) {
    int r = m0 + tr * 4 + i;
    if (r < N) {
      float4 o0, o1;
      o0.x = fmaxf(acc[i][0] + bias0.x, 0.f);
      o0.y = fmaxf(acc[i][1] + bias0.y, 0.f);
      o0.z = fmaxf(acc[i][2] + bias0.z, 0.f);
      o0.w = fmaxf(acc[i][3] + bias0.w, 0.f);
      o1.x = fmaxf(acc[i][4] + bias1.x, 0.f);
      o1.y = fmaxf(acc[i][5] + bias1.y, 0.f);
      o1.z = fmaxf(acc[i][6] + bias1.z, 0.f);
      o1.w = fmaxf(acc[i][7] + bias1.w, 0.f);
      *(float4*)&out[r * FEAT + tc * 4] = o0;
      *(float4*)&out[r * FEAT + tc * 4 + 64] = o1;
      if (out16) {
        uint2 p0, p1;
        p0.x = bf16rne(o0.x) | (bf16rne(o0.y) << 16);
        p0.y = bf16rne(o0.z) | (bf16rne(o0.w) << 16);
        p1.x = bf16rne(o1.x) | (bf16rne(o1.y) << 16);
        p1.y = bf16rne(o1.z) | (bf16rne(o1.w) << 16);
        *(uint2*)&out16[r * 64 + tc * 2] = p0;
        *(uint2*)&out16[r * 64 + 32 + tc * 2] = p1;
      }
    }
  }
}

// block-local running max over 64 sorted nodes, flush with int-atomicMax (vals >= 0)
__global__ __launch_bounds__(128) void k_pool(
    const float* __restrict__ h, const int* __restrict__ batch,
    float* __restrict__ g, int N) {
  int f = threadIdx.x;
  int base = blockIdx.x * 64;
  int end = min(base + 64, N);
  int cur = -1;
  float m = 0.f;
  for (int n = base; n < end; ++n) {
    int b = batch[n];
    if (b != cur) {
      if (cur >= 0) atomicMax((int*)&g[cur * FEAT + f], __float_as_int(m));
      cur = b;
      m = 0.f;
    }
    m = fmaxf(m, h[n * FEAT + f]);
  }
  if (cur >= 0) atomicMax((int*)&g[cur * FEAT + f], __float_as_int(m));
}

__global__ __launch_bounds__(64) void k_mlp(
    const float* __restrict__ g, const float* __restrict__ Wf1,
    const float* __restrict__ bf1, const float* __restrict__ Wf2,
    const float* __restrict__ bf2, float* __restrict__ out) {
  __shared__ float gr[128];
  __shared__ float h1[64];
  int gi = blockIdx.x, t = threadIdx.x;
  gr[t] = g[gi * FEAT + t];
  gr[t + 64] = g[gi * FEAT + 64 + t];
  __syncthreads();
  float acc = bf1[t];
#pragma unroll 4
  for (int k = 0; k < 128; ++k) acc += gr[k] * Wf1[k * 64 + t];
  h1[t] = fmaxf(acc, 0.f);
  __syncthreads();
  float logit = -INFINITY;
  if (t < 40) {
    float a = bf2[t];
#pragma unroll 4
    for (int k = 0; k < 64; ++k) a += h1[k] * Wf2[k * 40 + t];
    logit = a;
  }
  float m = logit;
#pragma unroll
  for (int off = 32; off; off >>= 1) m = fmaxf(m, __shfl_xor(m, off));
  float e = (t < 40) ? expf(logit - m) : 0.f;
  float s = e;
#pragma unroll
  for (int off = 32; off; off >>= 1) s += __shfl_xor(s, off);
  if (t < 40) out[gi * 40 + t] = logit - m - logf(s);
}

extern "C" void kernel_launch(void* const* d_in, const int* in_sizes, int n_in,
                              void* d_out, int out_size, void* d_ws, size_t ws_size,
                              hipStream_t stream) {
  const float* x = (const float*)d_in[0];
  const int* ei = (const int*)d_in[1];
  const int* batch = (const int*)d_in[2];
  const float* W1 = (const float*)d_in[3];
  const float* b1 = (const float*)d_in[4];
  const float* W2 = (const float*)d_in[5];
  const float* b2 = (const float*)d_in[6];
  const float* W3 = (const float*)d_in[7];
  const float* b3 = (const float*)d_in[8];
  const float* Wf1 = (const float*)d_in[9];
  const float* bf1 = (const float*)d_in[10];
  const float* Wf2 = (const float*)d_in[11];
  const float* bf2 = (const float*)d_in[12];
  float* out = (float*)d_out;

  const int N = NODES;
  const int E = in_sizes[1] / 2;  // 800000 original edges
  const int* src = ei;
  const int* dst = ei + E;

  char* ws = (char*)d_ws;
  size_t off = 0;
  auto carve = [&](size_t bytes) {
    void* p = ws + off;
    off += (bytes + 255) & ~(size_t)255;
    return p;
  };
  float* hA = (float*)carve((size_t)N * FEAT * 4);
  float* hB = (float*)carve((size_t)N * FEAT * 4);
  float* aggr = (float*)carve((size_t)N * FEAT * 4);  // aliased: binned lives here during build
  unsigned* h16 = (unsigned*)carve((size_t)N * 64 * 4);  // packed bf16 gather table
  int* zreg = (int*)carve((size_t)(256 + 256 + 64 * FEAT) * 4);  // bcount | bcur | g (contig)
  int* bcount = zreg;
  int* bcur = zreg + 256;
  float* g = (float*)(zreg + 512);
  int* bbase = (int*)carve((size_t)(NB + 1) * 4);
  int* offs = (int*)carve((size_t)(N + 1) * 4);
  int* adj = (int*)carve((size_t)2 * E * 4);
  uint2* binned = (uint2*)aggr;  // 12.8 MB <= 25.6 MB, dead until first k_nmax

  const int nzero = 256 + 256 + 64 * FEAT;
  const int nEB = (E + 4095) / 4096;  // 196 edge-chunk blocks

  // ---- build undirected CSR (two-level binned counting sort, coalesced writes) ----
  k_zero<<<(nzero + 255) / 256, 256, 0, stream>>>(zreg, nzero);
  k_bcount<<<nEB, 256, 0, stream>>>(src, dst, E, bcount);
  k_bscan<<<1, 256, 0, stream>>>(bcount, bbase, 2 * E);
  k_bin<<<nEB, 256, 0, stream>>>(src, dst, E, bbase, bcur, binned);
  k_build<<<NB, 256, 0, stream>>>(bbase, binned, offs, adj, N, 2 * E);

  // ---- packed-bf16 copy of x for the first gather ----
  k_cast<<<(N * 64 + 255) / 256, 256, 0, stream>>>(x, h16, N * 64);

  // ---- 3x MRConv (bf16 neighbor-max gather, concat-GEMM, ReLU + fused cast) ----
  k_nmax<<<N / 4, 256, 0, stream>>>(h16, x, offs, adj, aggr);
  k_gemm<<<(N + 63) / 64, 256, 0, stream>>>(x, aggr, W1, b1, hA, h16, N);
  k_nmax<<<N / 4, 256, 0, stream>>>(h16, hA, offs, adj, aggr);
  k_gemm<<<(N + 63) / 64, 256, 0, stream>>>(hA, aggr, W2, b2, hB, h16, N);
  k_nmax<<<N / 4, 256, 0, stream>>>(h16, hB, offs, adj, aggr);
  k_gemm<<<(N + 63) / 64, 256, 0, stream>>>(hB, aggr, W3, b3, hA, (unsigned*)nullptr, N);

  // ---- global max pool + MLP head + log_softmax ----
  k_pool<<<(N + 63) / 64, 128, 0, stream>>>(hA, batch, g, N);
  k_mlp<<<64, 64, 0, stream>>>(g, Wf1, bf1, Wf2, bf2, out);
}

// Round 4
// 417.520 us; speedup vs baseline: 2.0504x; 1.2656x over previous
//
#include <hip/hip_runtime.h>
#include <hip/hip_bf16.h>
#include <math.h>

#define NODES 50000
#define FEAT 128
#define NB 196          // ceil(50000/256) buckets of 256 nodes
#define BCAP 12288      // per-bucket adj capacity (mean 8192, sd ~90)

typedef __attribute__((ext_vector_type(4))) float f32x4;
typedef __attribute__((ext_vector_type(8))) short short8;
union UV { uint4 u; short8 s; };

__device__ __forceinline__ unsigned bf16rne(float x) {
  unsigned u = __float_as_uint(x);
  return (u + 0x7FFFu + ((u >> 16) & 1u)) >> 16;  // RNE, result in low 16
}

__global__ void k_zero(int* __restrict__ p, int n) {
  int i = blockIdx.x * blockDim.x + threadIdx.x;
  if (i < n) p[i] = 0;
}

// fp32 [N][128] -> packed bf16 pairs [N][64] u32
__global__ __launch_bounds__(256) void k_cast(const float* __restrict__ in,
                                              unsigned* __restrict__ out, int n2) {
  int i = blockIdx.x * 256 + threadIdx.x;
  if (i < n2) {
    float2 v = ((const float2*)in)[i];
    out[i] = bf16rne(v.x) | (bf16rne(v.y) << 16);
  }
}

// pack W [256][128] fp32 into MFMA B-fragment order: Wb[(ks*8+nf)*64+lane] = 8 bf16
__global__ __launch_bounds__(256) void k_wpack(const float* __restrict__ W,
                                               uint4* __restrict__ Wb) {
  int tid = blockIdx.x * 256 + threadIdx.x;  // 4096 total
  int lane = tid & 63, nf = (tid >> 6) & 7, ks = tid >> 9;
  int kb = ks * 32 + (lane >> 4) * 8;
  int col = nf * 16 + (lane & 15);
  uint4 r;
  r.x = bf16rne(W[(kb + 0) * FEAT + col]) | (bf16rne(W[(kb + 1) * FEAT + col]) << 16);
  r.y = bf16rne(W[(kb + 2) * FEAT + col]) | (bf16rne(W[(kb + 3) * FEAT + col]) << 16);
  r.z = bf16rne(W[(kb + 4) * FEAT + col]) | (bf16rne(W[(kb + 5) * FEAT + col]) << 16);
  r.w = bf16rne(W[(kb + 6) * FEAT + col]) | (bf16rne(W[(kb + 7) * FEAT + col]) << 16);
  Wb[tid] = r;
}

// Pass A: coarse bucket histogram (bucket = node >> 8), LDS-aggregated
__global__ __launch_bounds__(256) void k_bcount(const int* __restrict__ src,
                                                const int* __restrict__ dst,
                                                int E, int* __restrict__ bcount) {
  __shared__ int cnt[NB];
  int t = threadIdx.x;
  for (int i = t; i < NB; i += 256) cnt[i] = 0;
  __syncthreads();
  int base = blockIdx.x * 4096;
  int nE = min(4096, E - base);
  for (int k = t; k < nE; k += 256) {
    int s = src[base + k], d = dst[base + k];
    atomicAdd(&cnt[d >> 8], 1);
    atomicAdd(&cnt[s >> 8], 1);
  }
  __syncthreads();
  for (int i = t; i < NB; i += 256)
    if (cnt[i]) atomicAdd(&bcount[i], cnt[i]);
}

// exclusive scan of NB bucket counts -> bbase[NB+1]
__global__ __launch_bounds__(256) void k_bscan(const int* __restrict__ bcount,
                                               int* __restrict__ bbase, int twoE) {
  __shared__ int sc[256];
  int t = threadIdx.x;
  int v = (t < NB) ? bcount[t] : 0;
  sc[t] = v;
  __syncthreads();
  for (int off = 1; off < 256; off <<= 1) {
    int u = (t >= off) ? sc[t - off] : 0;
    __syncthreads();
    sc[t] += u;
    __syncthreads();
  }
  if (t < NB) bbase[t] = sc[t] - v;
  if (t == 0) bbase[NB] = twoE;
}

// Pass B: bucket-sort (d,s) pairs via LDS staging, flush in contiguous runs
__global__ __launch_bounds__(256) void k_bin(const int* __restrict__ src,
                                             const int* __restrict__ dst, int E,
                                             const int* __restrict__ bbase,
                                             int* __restrict__ bcur,
                                             uint2* __restrict__ binned) {
  __shared__ uint2 stage[8192];
  __shared__ int cnt[NB];
  __shared__ int lbase[NB];
  __shared__ int gbase[NB];
  __shared__ int lcur[NB];
  __shared__ int sc[256];
  int t = threadIdx.x;
  for (int i = t; i < NB; i += 256) cnt[i] = 0;
  __syncthreads();
  int base = blockIdx.x * 4096;
  int nE = min(4096, E - base);
  for (int k = t; k < nE; k += 256) {
    int s = src[base + k], d = dst[base + k];
    atomicAdd(&cnt[d >> 8], 1);
    atomicAdd(&cnt[s >> 8], 1);
  }
  __syncthreads();
  int v = (t < NB) ? cnt[t] : 0;
  sc[t] = v;
  __syncthreads();
  for (int off = 1; off < 256; off <<= 1) {
    int u = (t >= off) ? sc[t - off] : 0;
    __syncthreads();
    sc[t] += u;
    __syncthreads();
  }
  if (t < NB) {
    lbase[t] = sc[t] - v;
    lcur[t] = sc[t] - v;
  }
  __syncthreads();
  int total = sc[255];
  for (int k = t; k < nE; k += 256) {
    int s = src[base + k], d = dst[base + k];
    int p1 = atomicAdd(&lcur[d >> 8], 1);
    stage[p1] = make_uint2((unsigned)d, (unsigned)s);
    int p2 = atomicAdd(&lcur[s >> 8], 1);
    stage[p2] = make_uint2((unsigned)s, (unsigned)d);
  }
  __syncthreads();
  if (t < NB && cnt[t] > 0) gbase[t] = bbase[t] + atomicAdd(&bcur[t], cnt[t]);
  __syncthreads();
  for (int k = t; k < total; k += 256) {
    uint2 p = stage[k];
    int b = p.x >> 8;
    binned[gbase[b] + (k - lbase[b])] = p;
  }
}

// Pass C: per-bucket local CSR build entirely in LDS, coalesced writeout
__global__ __launch_bounds__(256) void k_build(const int* __restrict__ bbase,
                                               const uint2* __restrict__ binned,
                                               int* __restrict__ offs,
                                               int* __restrict__ adj,
                                               int N, int twoE) {
  __shared__ int hist[256];
  __shared__ int sc[256];
  __shared__ int lcur[256];
  __shared__ int adjS[BCAP];
  int b = blockIdx.x, t = threadIdx.x;
  int lo = bbase[b], hi = bbase[b + 1];
  int cntb = hi - lo;
  hist[t] = 0;
  __syncthreads();
  for (int k = t; k < cntb; k += 256) {
    uint2 p = binned[lo + k];
    atomicAdd(&hist[p.x & 255], 1);
  }
  __syncthreads();
  int v = hist[t];
  sc[t] = v;
  __syncthreads();
  for (int off = 1; off < 256; off <<= 1) {
    int u = (t >= off) ? sc[t - off] : 0;
    __syncthreads();
    sc[t] += u;
    __syncthreads();
  }
  int excl = sc[t] - v;
  lcur[t] = excl;
  int node = (b << 8) + t;
  if (node < N) offs[node] = lo + excl;
  if (b == NB - 1 && t == 0) offs[N] = twoE;
  __syncthreads();
  for (int k = t; k < cntb; k += 256) {
    uint2 p = binned[lo + k];
    int pos = atomicAdd(&lcur[p.x & 255], 1);
    adjS[pos] = (int)p.y;
  }
  __syncthreads();
  for (int k = t; k < cntb; k += 256) adj[lo + k] = adjS[k];
}

// aggr16[i][f-pair] = bf16( (deg>0) ? max_j bf16(h[j]) - bf16(h[i]) : 0 )
// one wave per node; lane handles features {2l, 2l+1} via packed-bf16 u32 gather
__global__ __launch_bounds__(256) void k_nmax(
    const unsigned* __restrict__ h16, const int* __restrict__ offs,
    const int* __restrict__ adj, unsigned* __restrict__ aggr16) {
  int i = blockIdx.x * 4 + (threadIdx.x >> 6);
  int lane = threadIdx.x & 63;
  int o0 = offs[i], o1 = offs[i + 1];
  float mlo0 = -INFINITY, mhi0 = -INFINITY;
  float mlo1 = -INFINITY, mhi1 = -INFINITY;
  int e = o0;
  for (; e + 4 <= o1; e += 4) {
    int j0 = adj[e], j1 = adj[e + 1], j2 = adj[e + 2], j3 = adj[e + 3];
    unsigned u0 = h16[(size_t)j0 * 64 + lane];
    unsigned u1 = h16[(size_t)j1 * 64 + lane];
    unsigned u2 = h16[(size_t)j2 * 64 + lane];
    unsigned u3 = h16[(size_t)j3 * 64 + lane];
    mlo0 = fmaxf(mlo0, __uint_as_float(u0 << 16));
    mhi0 = fmaxf(mhi0, __uint_as_float(u0 & 0xFFFF0000u));
    mlo1 = fmaxf(mlo1, __uint_as_float(u1 << 16));
    mhi1 = fmaxf(mhi1, __uint_as_float(u1 & 0xFFFF0000u));
    mlo0 = fmaxf(mlo0, __uint_as_float(u2 << 16));
    mhi0 = fmaxf(mhi0, __uint_as_float(u2 & 0xFFFF0000u));
    mlo1 = fmaxf(mlo1, __uint_as_float(u3 << 16));
    mhi1 = fmaxf(mhi1, __uint_as_float(u3 & 0xFFFF0000u));
  }
  for (; e < o1; ++e) {
    unsigned u0 = h16[(size_t)adj[e] * 64 + lane];
    mlo0 = fmaxf(mlo0, __uint_as_float(u0 << 16));
    mhi0 = fmaxf(mhi0, __uint_as_float(u0 & 0xFFFF0000u));
  }
  float mlo = fmaxf(mlo0, mlo1), mhi = fmaxf(mhi0, mhi1);
  unsigned us = h16[(size_t)i * 64 + lane];
  float hx = __uint_as_float(us << 16);
  float hy = __uint_as_float(us & 0xFFFF0000u);
  float rx = (o1 > o0) ? (mlo - hx) : 0.f;
  float ry = (o1 > o0) ? (mhi - hy) : 0.f;
  aggr16[(size_t)i * 64 + lane] = bf16rne(rx) | (bf16rne(ry) << 16);
}

// out16 = bf16(relu([A1|A2] @ W + bias)) via bf16 MFMA, fp32 accumulate.
// Block: 64 rows x 128 cols, 4 waves (16-row stripe each), K=256 in 8 steps.
__global__ __launch_bounds__(256) void k_gemm_mfma(
    const uint4* __restrict__ A1, const uint4* __restrict__ A2,
    const uint4* __restrict__ Wb, const float* __restrict__ bias,
    unsigned* __restrict__ out16, int N) {
  __shared__ uint4 Bs[4096];  // 64 KB; reused as Ct[64][132] ushort after MFMAs
  int t = threadIdx.x;
  int m0 = blockIdx.x * 64;
  for (int i = t; i < 4096; i += 256) Bs[i] = Wb[i];
  int wave = t >> 6, lane = t & 63;
  int kg = lane >> 4;
  int arow = m0 + wave * 16 + (lane & 15);
  int arc = min(arow, N - 1);
  const uint4* R1 = A1 + (size_t)arc * 16;
  const uint4* R2 = A2 + (size_t)arc * 16;
  f32x4 acc[8];
#pragma unroll
  for (int nf = 0; nf < 8; ++nf) acc[nf] = (f32x4){0.f, 0.f, 0.f, 0.f};
  __syncthreads();
#pragma unroll
  for (int ks = 0; ks < 8; ++ks) {
    UV a;
    a.u = (ks < 4) ? R1[ks * 4 + kg] : R2[(ks - 4) * 4 + kg];
#pragma unroll
    for (int nf = 0; nf < 8; ++nf) {
      UV b;
      b.u = Bs[(ks * 8 + nf) * 64 + lane];
      acc[nf] = __builtin_amdgcn_mfma_f32_16x16x32_bf16(a.s, b.s, acc[nf], 0, 0, 0);
    }
  }
  __syncthreads();
  unsigned short* Ct = (unsigned short*)Bs;  // [64][132] (132 => conflict-free banks)
#pragma unroll
  for (int nf = 0; nf < 8; ++nf) {
    float bc = bias[nf * 16 + (lane & 15)];
#pragma unroll
    for (int r = 0; r < 4; ++r) {
      int row = wave * 16 + kg * 4 + r;
      float v = fmaxf(acc[nf][r] + bc, 0.f);
      Ct[row * 132 + nf * 16 + (lane & 15)] = (unsigned short)bf16rne(v);
    }
  }
  __syncthreads();
  const unsigned* CtU = (const unsigned*)Bs;
  for (int i = t; i < 4096; i += 256) {
    int row = i >> 6, cp = i & 63;
    int gr = m0 + row;
    if (gr < N) out16[(size_t)gr * 64 + cp] = CtU[row * 66 + cp];
  }
}

// block-local running max over 64 sorted nodes on packed bf16, fp32 atomicMax flush
__global__ __launch_bounds__(64) void k_pool(
    const unsigned* __restrict__ h16, const int* __restrict__ batch,
    float* __restrict__ g, int N) {
  int f = threadIdx.x;  // u32 pair index: features 2f, 2f+1
  int base = blockIdx.x * 64;
  int end = min(base + 64, N);
  int cur = -1;
  float mx = 0.f, my = 0.f;
  for (int n = base; n < end; ++n) {
    int b = batch[n];
    if (b != cur) {
      if (cur >= 0) {
        atomicMax((int*)&g[cur * FEAT + 2 * f], __float_as_int(mx));
        atomicMax((int*)&g[cur * FEAT + 2 * f + 1], __float_as_int(my));
      }
      cur = b;
      mx = my = 0.f;
    }
    unsigned u = h16[(size_t)n * 64 + f];
    mx = fmaxf(mx, __uint_as_float(u << 16));
    my = fmaxf(my, __uint_as_float(u & 0xFFFF0000u));
  }
  if (cur >= 0) {
    atomicMax((int*)&g[cur * FEAT + 2 * f], __float_as_int(mx));
    atomicMax((int*)&g[cur * FEAT + 2 * f + 1], __float_as_int(my));
  }
}

__global__ __launch_bounds__(64) void k_mlp(
    const float* __restrict__ g, const float* __restrict__ Wf1,
    const float* __restrict__ bf1, const float* __restrict__ Wf2,
    const float* __restrict__ bf2, float* __restrict__ out) {
  __shared__ float gr[128];
  __shared__ float h1[64];
  int gi = blockIdx.x, t = threadIdx.x;
  gr[t] = g[gi * FEAT + t];
  gr[t + 64] = g[gi * FEAT + 64 + t];
  __syncthreads();
  float acc = bf1[t];
#pragma unroll 4
  for (int k = 0; k < 128; ++k) acc += gr[k] * Wf1[k * 64 + t];
  h1[t] = fmaxf(acc, 0.f);
  __syncthreads();
  float logit = -INFINITY;
  if (t < 40) {
    float a = bf2[t];
#pragma unroll 4
    for (int k = 0; k < 64; ++k) a += h1[k] * Wf2[k * 40 + t];
    logit = a;
  }
  float m = logit;
#pragma unroll
  for (int off = 32; off; off >>= 1) m = fmaxf(m, __shfl_xor(m, off));
  float e = (t < 40) ? expf(logit - m) : 0.f;
  float s = e;
#pragma unroll
  for (int off = 32; off; off >>= 1) s += __shfl_xor(s, off);
  if (t < 40) out[gi * 40 + t] = logit - m - logf(s);
}

extern "C" void kernel_launch(void* const* d_in, const int* in_sizes, int n_in,
                              void* d_out, int out_size, void* d_ws, size_t ws_size,
                              hipStream_t stream) {
  const float* x = (const float*)d_in[0];
  const int* ei = (const int*)d_in[1];
  const int* batch = (const int*)d_in[2];
  const float* W1 = (const float*)d_in[3];
  const float* b1 = (const float*)d_in[4];
  const float* W2 = (const float*)d_in[5];
  const float* b2 = (const float*)d_in[6];
  const float* W3 = (const float*)d_in[7];
  const float* b3 = (const float*)d_in[8];
  const float* Wf1 = (const float*)d_in[9];
  const float* bf1 = (const float*)d_in[10];
  const float* Wf2 = (const float*)d_in[11];
  const float* bf2 = (const float*)d_in[12];
  float* out = (float*)d_out;

  const int N = NODES;
  const int E = in_sizes[1] / 2;  // 800000 original edges
  const int* src = ei;
  const int* dst = ei + E;

  char* ws = (char*)d_ws;
  size_t off = 0;
  auto carve = [&](size_t bytes) {
    void* p = ws + off;
    off += (bytes + 255) & ~(size_t)255;
    return p;
  };
  unsigned* hA16 = (unsigned*)carve((size_t)N * 64 * 4);
  unsigned* hB16 = (unsigned*)carve((size_t)N * 64 * 4);
  unsigned* aggr16 = (unsigned*)carve((size_t)N * 64 * 4);  // binned aliases this
  uint4* Wb1 = (uint4*)carve(65536);
  uint4* Wb2 = (uint4*)carve(65536);
  uint4* Wb3 = (uint4*)carve(65536);
  int* zreg = (int*)carve((size_t)(256 + 256 + 64 * FEAT) * 4);  // bcount|bcur|g
  int* bcount = zreg;
  int* bcur = zreg + 256;
  float* g = (float*)(zreg + 512);
  int* bbase = (int*)carve((size_t)(NB + 1) * 4);
  int* offs = (int*)carve((size_t)(N + 1) * 4);
  int* adj = (int*)carve((size_t)2 * E * 4);
  uint2* binned = (uint2*)aggr16;  // 12.8 MB == 12.8 MB, dead until first k_nmax

  const int nzero = 256 + 256 + 64 * FEAT;
  const int nEB = (E + 4095) / 4096;  // 196 edge-chunk blocks
  const int nMB = (N + 63) / 64;      // 782 GEMM blocks

  // ---- build undirected CSR (two-level binned counting sort, coalesced writes) ----
  k_zero<<<(nzero + 255) / 256, 256, 0, stream>>>(zreg, nzero);
  k_bcount<<<nEB, 256, 0, stream>>>(src, dst, E, bcount);
  k_bscan<<<1, 256, 0, stream>>>(bcount, bbase, 2 * E);
  k_bin<<<nEB, 256, 0, stream>>>(src, dst, E, bbase, bcur, binned);
  k_build<<<NB, 256, 0, stream>>>(bbase, binned, offs, adj, N, 2 * E);

  // ---- pack x and the three weight matrices to bf16 ----
  k_cast<<<(N * 64 + 255) / 256, 256, 0, stream>>>(x, hA16, N * 64);
  k_wpack<<<16, 256, 0, stream>>>(W1, Wb1);
  k_wpack<<<16, 256, 0, stream>>>(W2, Wb2);
  k_wpack<<<16, 256, 0, stream>>>(W3, Wb3);

  // ---- 3x MRConv (bf16 gather-max, bf16 MFMA concat-GEMM + ReLU) ----
  k_nmax<<<N / 4, 256, 0, stream>>>(hA16, offs, adj, aggr16);
  k_gemm_mfma<<<nMB, 256, 0, stream>>>((const uint4*)hA16, (const uint4*)aggr16, Wb1, b1, hB16, N);
  k_nmax<<<N / 4, 256, 0, stream>>>(hB16, offs, adj, aggr16);
  k_gemm_mfma<<<nMB, 256, 0, stream>>>((const uint4*)hB16, (const uint4*)aggr16, Wb2, b2, hA16, N);
  k_nmax<<<N / 4, 256, 0, stream>>>(hA16, offs, adj, aggr16);
  k_gemm_mfma<<<nMB, 256, 0, stream>>>((const uint4*)hA16, (const uint4*)aggr16, Wb3, b3, hB16, N);

  // ---- global max pool + MLP head + log_softmax ----
  k_pool<<<(N + 63) / 64, 64, 0, stream>>>(hB16, batch, g, N);
  k_mlp<<<64, 64, 0, stream>>>(g, Wf1, bf1, Wf2, bf2, out);
}